// Round 1
// baseline (111.906 us; speedup 1.0000x reference)
//
#include <hip/hip_runtime.h>
#include <hip/hip_bf16.h>

// AssignIndex: out = arr, except out[index, :] = element.
// arr: [65536, 1024] f32, element: [1024] f32, index: scalar int (device 1-elem array).
// Pure memory-bound full copy; float4 vectorized grid-stride loop.

#define D 1024
#define D4 (D / 4)   // 256 float4 per row -> row = i4 >> 8

__global__ __launch_bounds__(256) void assign_index_kernel(
    const float4* __restrict__ arr,
    const int* __restrict__ index_p,
    const float4* __restrict__ elem,
    float4* __restrict__ out,
    long long n4)
{
    const int index = *index_p;  // uniform scalar load, cached
    long long i = (long long)blockIdx.x * blockDim.x + threadIdx.x;
    const long long stride = (long long)gridDim.x * blockDim.x;
    for (; i < n4; i += stride) {
        long long row = i >> 8;          // D4 == 256
        float4 v = arr[i];
        if (row == (long long)index) {
            v = elem[i & (D4 - 1)];
        }
        out[i] = v;
    }
}

extern "C" void kernel_launch(void* const* d_in, const int* in_sizes, int n_in,
                              void* d_out, int out_size, void* d_ws, size_t ws_size,
                              hipStream_t stream) {
    const float4* arr  = (const float4*)d_in[0];
    const int*    idx  = (const int*)d_in[1];
    const float4* elem = (const float4*)d_in[2];
    float4* out = (float4*)d_out;

    const long long n4 = (long long)out_size / 4;  // 65536*1024/4 = 16,777,216
    const int block = 256;
    // Memory-bound: cap grid at 256 CUs x 8 blocks, grid-stride the rest.
    long long want = (n4 + block - 1) / block;
    int grid = (int)(want < 2048 ? want : 2048);

    assign_index_kernel<<<grid, block, 0, stream>>>(arr, idx, elem, out, n4);
}

// Round 2
// 80.797 us; speedup vs baseline: 1.3850x; 1.3850x over previous
//
#include <hip/hip_runtime.h>
#include <hip/hip_bf16.h>

// AssignIndex: out = arr, except out[index, :] = element.
// arr: [65536, 1024] f32 (256 MiB), element: [1024] f32, index: device scalar int.
// Memory-bound copy. One-shot grid, 4 float4 per thread (MLP=4), nontemporal
// stores so the output stream doesn't evict arr from L2/L3.

typedef float floatx4 __attribute__((ext_vector_type(4)));

#define D4 256          // 1024 floats / 4 per float4; row = i4 >> 8
#define PER_THREAD 4
#define BLOCK 256

__global__ __launch_bounds__(BLOCK) void assign_index_kernel(
    const floatx4* __restrict__ arr,
    const int* __restrict__ index_p,
    const floatx4* __restrict__ elem,
    floatx4* __restrict__ out,
    long long n4)
{
    const int index = *index_p;  // uniform scalar load
    const long long base = (long long)blockIdx.x * (BLOCK * PER_THREAD) + threadIdx.x;

    if (base + (PER_THREAD - 1) * BLOCK < n4) {
        // fast path: no bounds checks, 4 outstanding loads
        floatx4 v[PER_THREAD];
#pragma unroll
        for (int k = 0; k < PER_THREAD; ++k)
            v[k] = arr[base + k * BLOCK];
#pragma unroll
        for (int k = 0; k < PER_THREAD; ++k) {
            long long i = base + k * BLOCK;
            if ((int)(i >> 8) == index)
                v[k] = elem[i & (D4 - 1)];
            __builtin_nontemporal_store(v[k], &out[i]);
        }
    } else {
#pragma unroll
        for (int k = 0; k < PER_THREAD; ++k) {
            long long i = base + k * BLOCK;
            if (i < n4) {
                floatx4 v = arr[i];
                if ((int)(i >> 8) == index)
                    v = elem[i & (D4 - 1)];
                __builtin_nontemporal_store(v, &out[i]);
            }
        }
    }
}

extern "C" void kernel_launch(void* const* d_in, const int* in_sizes, int n_in,
                              void* d_out, int out_size, void* d_ws, size_t ws_size,
                              hipStream_t stream) {
    const floatx4* arr  = (const floatx4*)d_in[0];
    const int*     idx  = (const int*)d_in[1];
    const floatx4* elem = (const floatx4*)d_in[2];
    floatx4* out = (floatx4*)d_out;

    const long long n4 = (long long)out_size / 4;  // 16,777,216
    const long long per_block = BLOCK * PER_THREAD; // 1024 float4 per block
    const int grid = (int)((n4 + per_block - 1) / per_block);  // 16384

    assign_index_kernel<<<grid, BLOCK, 0, stream>>>(arr, idx, elem, out, n4);
}